// Round 5
// baseline (149.896 us; speedup 1.0000x reference)
//
#include <hip/hip_runtime.h>
#include <stdint.h>
#include <stddef.h>

// ---------------- types ----------------
typedef __attribute__((ext_vector_type(8))) short bf16x8;          // MFMA A/B frag (8 bf16)
typedef __attribute__((ext_vector_type(8))) unsigned short u16x8;  // 16B store
typedef __attribute__((ext_vector_type(4))) float f32x4;           // MFMA C/D frag

typedef const __attribute__((address_space(1))) void* gptr1_t;
typedef __attribute__((address_space(3))) void* lptr3_t;

#define GLOAD_LDS16(gp, lp) \
  __builtin_amdgcn_global_load_lds((gptr1_t)(gp), (lptr3_t)(lp), 16, 0, 0)

__device__ __forceinline__ uint16_t f2bf(float f) {
  uint32_t u = __builtin_bit_cast(uint32_t, f);
  u += 0x7fffu + ((u >> 16) & 1u);   // RNE
  return (uint16_t)(u >> 16);
}

// ---------------- problem constants ----------------
#define MB   16384      // batch
#define NP   256        // W*H positions
#define KDIM 1024       // NP*EMB
#define NDIM 1024       // OUT

// ---------------- kernel 1: Bt[n][k] = bf16(W_dense[k][n]); block(0,0) also builds
// Webf[c][e] = bf16(W_embed[c][e] + b_embed[e]) (1024x4 = 8 KB table) ----------------
__global__ void build_bt_webf_kernel(const float* __restrict__ Wd,
                                     const float* __restrict__ We,
                                     const float* __restrict__ be,
                                     uint16_t* __restrict__ Bt,
                                     uint16_t* __restrict__ Webf) {
  __shared__ uint16_t tile[32][33];               // +1 pad: no bank conflicts
  const int k0 = blockIdx.y * 32;
  const int n0 = blockIdx.x * 32;
  const int tx = threadIdx.x;                     // 0..31
  const int ty = threadIdx.y;                     // 0..7
  #pragma unroll
  for (int r = 0; r < 32; r += 8)
    tile[ty + r][tx] = f2bf(Wd[(size_t)(k0 + ty + r) * NDIM + n0 + tx]);
  __syncthreads();
  #pragma unroll
  for (int r = 0; r < 32; r += 8)
    Bt[(size_t)(n0 + ty + r) * KDIM + k0 + tx] = tile[tx][ty + r];

  if (blockIdx.x == 0 && blockIdx.y == 0) {       // fold in the tiny Webf build
    const int flat = ty * 32 + tx;                // 0..255
    const float4 bb = *(const float4*)be;
    #pragma unroll
    for (int c = 0; c < 4; ++c) {                 // 4 classes per thread
      const int cls = flat * 4 + c;
      const float4 e = *(const float4*)(We + (size_t)cls * 4);
      ushort4 o = { f2bf(e.x + bb.x), f2bf(e.y + bb.y),
                    f2bf(e.z + bb.z), f2bf(e.w + bb.w) };
      *(ushort4*)(Webf + (size_t)cls * 4) = o;
    }
  }
}

// ---------------- kernel 2: fused gather + bf16 GEMM ----------------
// C[b][n] = sum_k A[b][k]*Bt[n][k] + bias[n],  A[b][p*4+e] = Webf[x[b][p]][e].
// Structure == R3 winner (BM=128,BN=128,BK=64 as two 32-K half-tiles); only the
// As producer changed: LDS-resident table gather (ds_read_b64) one iter ahead,
// written with the exact same lane-contiguous b128 layout global_load_lds used.
#define BM  128
#define BN  128
#define BKH 32
#define BK  64
#define NK  (KDIM / BK)   // 16

__global__ __launch_bounds__(256) void gemm_fused_kernel(
    const int* __restrict__ x,
    const uint16_t* __restrict__ Webf,
    const uint16_t* __restrict__ Bt,
    const float* __restrict__ bias,
    float* __restrict__ C) {
  __shared__ uint16_t As[2][BM * BKH];   // 2 x 8 KB
  __shared__ uint16_t Bs[2][BN * BKH];   // 2 x 8 KB
  __shared__ uint16_t Tab[KDIM * 4];     // 8 KB embed table

  const int tid  = threadIdx.x;
  const int bm   = blockIdx.x;       // 128 m-tiles
  const int bn   = blockIdx.y;       // 8 n-tiles
  const int wave = tid >> 6;
  const int lane = tid & 63;
  const int wr   = wave >> 1;        // 2x2 wave grid, 64x64 per wave
  const int wc   = wave & 1;
  const int lm   = lane & 15;
  const int q    = lane >> 4;

  const int row0 = bm * BM;
  const int col0 = bn * BN;

  // staging geometry (identical to R3)
  const int srow = tid >> 2;          // 0..63
  const int scol = (tid & 3) * 8;     // 8 bf16 = 16B

  // A gather addressing: thread owns As[h][srow][scol..+8] and As[h][64+srow][..]
  // = positions p = kt*16 + h*8 + (tid&3)*2 + {0,1} of rows srow / 64+srow.
  const int pc = (tid & 3) * 2;
  const int* xr0 = x + (size_t)(row0 + srow)      * NP + pc;
  const int* xr1 = x + (size_t)(row0 + 64 + srow) * NP + pc;

  // ---- prologue: x for kt=0 in flight, stage table, gather kt=0 ----
  int2 xa0 = *(const int2*)(xr0);      // rs0 h0
  int2 xb0 = *(const int2*)(xr0 + 8);  // rs0 h1
  int2 xa1 = *(const int2*)(xr1);      // rs1 h0
  int2 xb1 = *(const int2*)(xr1 + 8);  // rs1 h1

  {
    u16x8 t0 = *(const u16x8*)(Webf + tid * 16);
    u16x8 t1 = *(const u16x8*)(Webf + tid * 16 + 8);
    *(u16x8*)(Tab + tid * 16)     = t0;
    *(u16x8*)(Tab + tid * 16 + 8) = t1;
  }
  __syncthreads();                     // table visible to all

  ushort4 g[8];
#define GATHER_ALL()                                          \
  g[0] = *(const ushort4*)(Tab + (size_t)xa0.x * 4);          \
  g[1] = *(const ushort4*)(Tab + (size_t)xa0.y * 4);          \
  g[2] = *(const ushort4*)(Tab + (size_t)xb0.x * 4);          \
  g[3] = *(const ushort4*)(Tab + (size_t)xb0.y * 4);          \
  g[4] = *(const ushort4*)(Tab + (size_t)xa1.x * 4);          \
  g[5] = *(const ushort4*)(Tab + (size_t)xa1.y * 4);          \
  g[6] = *(const ushort4*)(Tab + (size_t)xb1.x * 4);          \
  g[7] = *(const ushort4*)(Tab + (size_t)xb1.y * 4);

  GATHER_ALL();                        // values for kt=0

  f32x4 acc[4][4];
  #pragma unroll
  for (int i = 0; i < 4; i++)
    #pragma unroll
    for (int j = 0; j < 4; j++)
      acc[i][j] = (f32x4){0.f, 0.f, 0.f, 0.f};

  for (int kt = 0; kt < NK; ++kt) {
    const int k0 = kt * BK;

    // B staging: async global->LDS (as R3)
    #pragma unroll
    for (int h = 0; h < 2; ++h) {
      GLOAD_LDS16(Bt + (size_t)(col0      + srow) * KDIM + k0 + h * BKH + scol, Bs[h] + tid * 8);
      GLOAD_LDS16(Bt + (size_t)(col0 + 64 + srow) * KDIM + k0 + h * BKH + scol, Bs[h] + 2048 + tid * 8);
    }

    // x prefetch for kt+1 (coalesced; drained by the barrier alongside B)
    if (kt + 1 < NK) {
      const int off = (kt + 1) * 16;
      xa0 = *(const int2*)(xr0 + off);
      xb0 = *(const int2*)(xr0 + off + 8);
      xa1 = *(const int2*)(xr1 + off);
      xb1 = *(const int2*)(xr1 + off + 8);
    }

    // write this iter's gathered A (lane-contiguous b128, layout == R3)
    *(u16x8*)(As[0] + tid * 8)        = (u16x8){ g[0].x,g[0].y,g[0].z,g[0].w, g[1].x,g[1].y,g[1].z,g[1].w };
    *(u16x8*)(As[1] + tid * 8)        = (u16x8){ g[2].x,g[2].y,g[2].z,g[2].w, g[3].x,g[3].y,g[3].z,g[3].w };
    *(u16x8*)(As[0] + 2048 + tid * 8) = (u16x8){ g[4].x,g[4].y,g[4].z,g[4].w, g[5].x,g[5].y,g[5].z,g[5].w };
    *(u16x8*)(As[1] + 2048 + tid * 8) = (u16x8){ g[6].x,g[6].y,g[6].z,g[6].w, g[7].x,g[7].y,g[7].z,g[7].w };

    __syncthreads();

    // gather kt+1 now — overlaps the MFMA phase (last iter re-gathers stale
    // but valid indices; result unused)
    GATHER_ALL();

    #pragma unroll
    for (int h = 0; h < 2; ++h) {
      bf16x8 af[4], bfr[4];
      #pragma unroll
      for (int i = 0; i < 4; i++)
        af[i] = *(const bf16x8*)(As[h] + (wr * 64 + i * 16 + lm) * BKH + q * 8);
      #pragma unroll
      for (int j = 0; j < 4; j++)
        bfr[j] = *(const bf16x8*)(Bs[h] + (wc * 64 + j * 16 + lm) * BKH + q * 8);

      #pragma unroll
      for (int i = 0; i < 4; i++)
        #pragma unroll
        for (int j = 0; j < 4; j++)
          acc[i][j] = __builtin_amdgcn_mfma_f32_16x16x32_bf16(af[i], bfr[j], acc[i][j], 0, 0, 0);
    }

    __syncthreads();
  }

  // epilogue: D[row = q*4 + r][col = lm] per 16x16 frag (m89/m91-verified)
  float bvals[4];
  #pragma unroll
  for (int j = 0; j < 4; j++)
    bvals[j] = bias[col0 + wc * 64 + j * 16 + lm];

  #pragma unroll
  for (int i = 0; i < 4; i++) {
    const int rbase = row0 + wr * 64 + i * 16 + q * 4;
    #pragma unroll
    for (int j = 0; j < 4; j++) {
      const int col = col0 + wc * 64 + j * 16 + lm;
      #pragma unroll
      for (int r = 0; r < 4; r++)
        C[(size_t)(rbase + r) * NDIM + col] = acc[i][j][r] + bvals[j];
    }
  }
}

// ---------------- fallback (workspace too small): fp32 naive ----------------
__global__ void naive_kernel(const int* __restrict__ x,
                             const float* __restrict__ We,
                             const float* __restrict__ be,
                             const float* __restrict__ Wd,
                             const float* __restrict__ bd,
                             float* __restrict__ out) {
  __shared__ float emb[KDIM];
  const int b = blockIdx.x;
  const int tid = threadIdx.x;
  {
    const int cls = x[(size_t)b * NP + tid];
    const float4 e  = *(const float4*)(We + (size_t)cls * 4);
    const float4 bb = *(const float4*)be;
    emb[tid * 4 + 0] = e.x + bb.x;
    emb[tid * 4 + 1] = e.y + bb.y;
    emb[tid * 4 + 2] = e.z + bb.z;
    emb[tid * 4 + 3] = e.w + bb.w;
  }
  __syncthreads();
  float acc0 = bd[tid], acc1 = bd[tid + 256], acc2 = bd[tid + 512], acc3 = bd[tid + 768];
  for (int k = 0; k < KDIM; ++k) {
    const float a = emb[k];
    const float* w = Wd + (size_t)k * NDIM + tid;
    acc0 += a * w[0];
    acc1 += a * w[256];
    acc2 += a * w[512];
    acc3 += a * w[768];
  }
  float* o = out + (size_t)b * NDIM + tid;
  o[0] = acc0; o[256] = acc1; o[512] = acc2; o[768] = acc3;
}

// ---------------- launch ----------------
extern "C" void kernel_launch(void* const* d_in, const int* in_sizes, int n_in,
                              void* d_out, int out_size, void* d_ws, size_t ws_size,
                              hipStream_t stream) {
  const int*   x  = (const int*)d_in[0];
  const float* We = (const float*)d_in[1];
  const float* be = (const float*)d_in[2];
  const float* Wd = (const float*)d_in[3];
  const float* bd = (const float*)d_in[4];
  float* out = (float*)d_out;

  const size_t needW = (size_t)KDIM * 4 * sizeof(uint16_t);     // Webf: 8 KB
  const size_t needB = (size_t)NDIM * KDIM * sizeof(uint16_t);  // Bt: 2 MB

  if (ws_size >= needW + needB) {
    uint16_t* Webf = (uint16_t*)d_ws;
    uint16_t* Btw  = (uint16_t*)((char*)d_ws + needW);
    build_bt_webf_kernel<<<dim3(NDIM / 32, KDIM / 32), dim3(32, 8), 0, stream>>>(Wd, We, be, Btw, Webf);
    gemm_fused_kernel<<<dim3(MB / BM, NDIM / BN), 256, 0, stream>>>(x, Webf, Btw, bd, out);
  } else {
    naive_kernel<<<MB, 256, 0, stream>>>(x, We, be, Wd, bd, out);
  }
}

// Round 6
// 146.158 us; speedup vs baseline: 1.0256x; 1.0256x over previous
//
#include <hip/hip_runtime.h>
#include <stdint.h>
#include <stddef.h>

// ---------------- types ----------------
typedef __attribute__((ext_vector_type(8))) short bf16x8;          // MFMA A/B frag (8 bf16)
typedef __attribute__((ext_vector_type(8))) unsigned short u16x8;  // 16B store
typedef __attribute__((ext_vector_type(4))) float f32x4;           // MFMA C/D frag

typedef const __attribute__((address_space(1))) void* gptr1_t;
typedef __attribute__((address_space(3))) void* lptr3_t;

#define GLOAD_LDS16(gp, lp) \
  __builtin_amdgcn_global_load_lds((gptr1_t)(gp), (lptr3_t)(lp), 16, 0, 0)

__device__ __forceinline__ uint16_t f2bf(float f) {
  uint32_t u = __builtin_bit_cast(uint32_t, f);
  u += 0x7fffu + ((u >> 16) & 1u);   // RNE
  return (uint16_t)(u >> 16);
}

// ---------------- problem constants ----------------
#define MB   16384      // batch
#define NP   256        // W*H positions
#define KDIM 1024       // NP*EMB
#define NDIM 1024       // OUT

#define NBLK_A  (MB * NP / 2 / 256)   // 8192 blocks for A-gather (2 pos/thread)
#define NBLK_BT ((NDIM / 32) * (KDIM / 32))  // 1024 blocks for Bt transpose

// ---------------- kernel 1 (merged prep): A-gather + Bt transpose ----------------
// blocks [0, 8192): A[b][p*4+e] = bf16(W_embed[x[b][p]][e] + b_embed[e])
// blocks [8192, 9216): Bt[n][k] = bf16(W_dense[k][n])
__global__ void prep_kernel(const int* __restrict__ x,
                            const float* __restrict__ We,
                            const float* __restrict__ be,
                            const float* __restrict__ Wd,
                            uint16_t* __restrict__ A,
                            uint16_t* __restrict__ Bt) {
  __shared__ uint16_t tile[32][33];               // used by Bt part only (+1 pad)
  const int bid = blockIdx.x;
  const int tid = threadIdx.x;

  if (bid < NBLK_A) {
    const int t = bid * 256 + tid;                // over MB*NP/2
    const int2 cls = ((const int2*)x)[t];
    const float4 e0 = *(const float4*)(We + (size_t)cls.x * 4);  // 16 KB table, L1-hot
    const float4 e1 = *(const float4*)(We + (size_t)cls.y * 4);
    const float4 bb = *(const float4*)be;
    u16x8 o = { f2bf(e0.x + bb.x), f2bf(e0.y + bb.y), f2bf(e0.z + bb.z), f2bf(e0.w + bb.w),
                f2bf(e1.x + bb.x), f2bf(e1.y + bb.y), f2bf(e1.z + bb.z), f2bf(e1.w + bb.w) };
    *(u16x8*)(A + (size_t)t * 8) = o;             // coalesced 16B stores
  } else {
    const int b2 = bid - NBLK_A;
    const int n0 = (b2 & 31) * 32;
    const int k0 = (b2 >> 5) * 32;
    const int tx = tid & 31;                      // 0..31
    const int ty = tid >> 5;                      // 0..7
    #pragma unroll
    for (int r = 0; r < 32; r += 8)
      tile[ty + r][tx] = f2bf(Wd[(size_t)(k0 + ty + r) * NDIM + n0 + tx]);
    __syncthreads();
    #pragma unroll
    for (int r = 0; r < 32; r += 8)
      Bt[(size_t)(n0 + ty + r) * KDIM + k0 + tx] = tile[tx][ty + r];
  }
}

// ---------------- kernel 2: bf16 GEMM, C = A @ Bt^T + bias (R3 winner) ----------------
// A: M x K bf16 row-major; Bt: N x K bf16 row-major; C: M x N fp32.
// BK=64 staged as TWO independent 128x32 half-tiles: preserves the verified
// BK=32 LDS row-stride (64B), 32 MFMAs per barrier-pair, 16 iters.
#define BM  128
#define BN  128
#define BKH 32
#define BK  64
#define NK  (KDIM / BK)   // 16

__global__ __launch_bounds__(256) void gemm_bt_kernel(
    const uint16_t* __restrict__ A,
    const uint16_t* __restrict__ Bt,
    const float* __restrict__ bias,
    float* __restrict__ C) {
  __shared__ uint16_t As[2][BM * BKH];   // 2 x 8 KB
  __shared__ uint16_t Bs[2][BN * BKH];   // 2 x 8 KB

  const int tid  = threadIdx.x;
  const int bm   = blockIdx.x;       // 128 m-tiles
  const int bn   = blockIdx.y;       // 8 n-tiles
  const int wave = tid >> 6;
  const int lane = tid & 63;
  const int wr   = wave >> 1;        // 2x2 wave grid, 64x64 per wave
  const int wc   = wave & 1;
  const int lm   = lane & 15;
  const int q    = lane >> 4;

  const int row0 = bm * BM;
  const int col0 = bn * BN;

  // staging: each thread loads 16B per call; lane-contiguous => row-major half-tile
  const int srow = tid >> 2;          // 0..63
  const int scol = (tid & 3) * 8;     // 8 bf16 = 16B

  f32x4 acc[4][4];
  #pragma unroll
  for (int i = 0; i < 4; i++)
    #pragma unroll
    for (int j = 0; j < 4; j++)
      acc[i][j] = (f32x4){0.f, 0.f, 0.f, 0.f};

  for (int kt = 0; kt < NK; ++kt) {
    const int k0 = kt * BK;
    #pragma unroll
    for (int h = 0; h < 2; ++h) {
      GLOAD_LDS16(A  + (size_t)(row0      + srow) * KDIM + k0 + h * BKH + scol, As[h] + tid * 8);
      GLOAD_LDS16(A  + (size_t)(row0 + 64 + srow) * KDIM + k0 + h * BKH + scol, As[h] + 2048 + tid * 8);
      GLOAD_LDS16(Bt + (size_t)(col0      + srow) * KDIM + k0 + h * BKH + scol, Bs[h] + tid * 8);
      GLOAD_LDS16(Bt + (size_t)(col0 + 64 + srow) * KDIM + k0 + h * BKH + scol, Bs[h] + 2048 + tid * 8);
    }
    __syncthreads();

    #pragma unroll
    for (int h = 0; h < 2; ++h) {
      bf16x8 af[4], bfr[4];
      #pragma unroll
      for (int i = 0; i < 4; i++)
        af[i] = *(const bf16x8*)(As[h] + (wr * 64 + i * 16 + lm) * BKH + q * 8);
      #pragma unroll
      for (int j = 0; j < 4; j++)
        bfr[j] = *(const bf16x8*)(Bs[h] + (wc * 64 + j * 16 + lm) * BKH + q * 8);

      #pragma unroll
      for (int i = 0; i < 4; i++)
        #pragma unroll
        for (int j = 0; j < 4; j++)
          acc[i][j] = __builtin_amdgcn_mfma_f32_16x16x32_bf16(af[i], bfr[j], acc[i][j], 0, 0, 0);
    }

    __syncthreads();
  }

  // epilogue: D[row = q*4 + r][col = lm] per 16x16 frag (m89/m91-verified).
  // Non-temporal stores: C is write-once, never re-read — skip L2 allocation.
  float bvals[4];
  #pragma unroll
  for (int j = 0; j < 4; j++)
    bvals[j] = bias[col0 + wc * 64 + j * 16 + lm];

  #pragma unroll
  for (int i = 0; i < 4; i++) {
    const int rbase = row0 + wr * 64 + i * 16 + q * 4;
    #pragma unroll
    for (int j = 0; j < 4; j++) {
      const int col = col0 + wc * 64 + j * 16 + lm;
      #pragma unroll
      for (int r = 0; r < 4; r++)
        __builtin_nontemporal_store(acc[i][j][r] + bvals[j],
                                    C + (size_t)(rbase + r) * NDIM + col);
    }
  }
}

// ---------------- fallback (workspace too small): fp32 naive ----------------
__global__ void naive_kernel(const int* __restrict__ x,
                             const float* __restrict__ We,
                             const float* __restrict__ be,
                             const float* __restrict__ Wd,
                             const float* __restrict__ bd,
                             float* __restrict__ out) {
  __shared__ float emb[KDIM];
  const int b = blockIdx.x;
  const int tid = threadIdx.x;
  {
    const int cls = x[(size_t)b * NP + tid];
    const float4 e  = *(const float4*)(We + (size_t)cls * 4);
    const float4 bb = *(const float4*)be;
    emb[tid * 4 + 0] = e.x + bb.x;
    emb[tid * 4 + 1] = e.y + bb.y;
    emb[tid * 4 + 2] = e.z + bb.z;
    emb[tid * 4 + 3] = e.w + bb.w;
  }
  __syncthreads();
  float acc0 = bd[tid], acc1 = bd[tid + 256], acc2 = bd[tid + 512], acc3 = bd[tid + 768];
  for (int k = 0; k < KDIM; ++k) {
    const float a = emb[k];
    const float* w = Wd + (size_t)k * NDIM + tid;
    acc0 += a * w[0];
    acc1 += a * w[256];
    acc2 += a * w[512];
    acc3 += a * w[768];
  }
  float* o = out + (size_t)b * NDIM + tid;
  o[0] = acc0; o[256] = acc1; o[512] = acc2; o[768] = acc3;
}

// ---------------- launch ----------------
extern "C" void kernel_launch(void* const* d_in, const int* in_sizes, int n_in,
                              void* d_out, int out_size, void* d_ws, size_t ws_size,
                              hipStream_t stream) {
  const int*   x  = (const int*)d_in[0];
  const float* We = (const float*)d_in[1];
  const float* be = (const float*)d_in[2];
  const float* Wd = (const float*)d_in[3];
  const float* bd = (const float*)d_in[4];
  float* out = (float*)d_out;

  const size_t needA = (size_t)MB * KDIM * sizeof(uint16_t);    // 33.5 MB
  const size_t needB = (size_t)NDIM * KDIM * sizeof(uint16_t);  // 2 MB

  if (ws_size >= needA + needB) {
    uint16_t* Aw  = (uint16_t*)d_ws;
    uint16_t* Btw = (uint16_t*)((char*)d_ws + needA);
    prep_kernel<<<NBLK_A + NBLK_BT, 256, 0, stream>>>(x, We, be, Wd, Aw, Btw);
    gemm_bt_kernel<<<dim3(MB / BM, NDIM / BN), 256, 0, stream>>>(Aw, Btw, bd, out);
  } else {
    naive_kernel<<<MB, 256, 0, stream>>>(x, We, be, Wd, bd, out);
  }
}